// Round 7
// baseline (401.390 us; speedup 1.0000x reference)
//
#include <hip/hip_runtime.h>
#include <math.h>

// ---------------------------------------------------------------------------
// SAGPool GNN forward: 3x [GCNConv -> SAGPool(top-k) -> readout] + MLP head.
// B=32 graphs x N=2048 nodes; E=524288; 128 feats; K = 1024/512/256.
// R7 changes vs R6 (399us; matmul 45us latency-bound, W-reads 4-way conflict):
//   - matmul: col remap {4c,64+4c} -> W reads 2-way (free); register
//     double-buffer prefetch of next k-chunk across the barrier.
//   - k_pool absorbs k_readout1: readout over kept list done in-block
//     (scale+kept already in LDS), writes final per-graph [max|mean] (gout).
//   - pool radix: 16 per-wave replicated histograms (no cross-wave atomic
//     contention) + wave-shuffle scan (3 barriers/round vs 16).
//   - dispatches 18 -> 15.
// ---------------------------------------------------------------------------

namespace {

constexpr int B_  = 32;
constexpr int N_  = 2048;
constexpr int NT  = B_ * N_;        // 65536
constexpr int E_  = B_ * 16384;     // 524288
constexpr int NCLS = 10;
constexpr int AST = 132;            // LDS row stride (128 + 4 pad)

// ---- CSR build -------------------------------------------------------------
__global__ void k_count(const int* __restrict__ dst, int* __restrict__ cnt) {
  int e = blockIdx.x * 256 + threadIdx.x;
  if (e < E_) atomicAdd(&cnt[dst[e]], 1);
}

__global__ void k_scan1(const int* __restrict__ cnt, int* __restrict__ off,
                        int* __restrict__ bsum) {
  __shared__ int s[256];
  int t = threadIdx.x;
  int i = blockIdx.x * 256 + t;
  int v = cnt[i];
  s[t] = v;
  __syncthreads();
  for (int d = 1; d < 256; d <<= 1) {
    int add = (t >= d) ? s[t - d] : 0;
    __syncthreads();
    s[t] += add;
    __syncthreads();
  }
  off[i] = s[t] - v;  // exclusive within block
  if (t == 255) bsum[blockIdx.x] = s[255];
}

// adds bsum prefix (block rescans bsum itself), writes cursor, and computes
// layer-0 deg/dinv/selfw + scale=1.
__global__ void k_scan3(int* __restrict__ off, const int* __restrict__ bsum,
                        const int* __restrict__ cnt, int* __restrict__ cursor,
                        float* __restrict__ dinv, float* __restrict__ selfw,
                        float* __restrict__ scale) {
  __shared__ int sb[256];
  int t = threadIdx.x;
  sb[t] = bsum[t];
  __syncthreads();
  for (int d = 1; d < 256; d <<= 1) {
    int add = (t >= d) ? sb[t - d] : 0;
    __syncthreads();
    sb[t] += add;
    __syncthreads();
  }
  int prefix = (blockIdx.x == 0) ? 0 : sb[blockIdx.x - 1];
  int i = blockIdx.x * 256 + t;
  int v = off[i] + prefix;
  off[i] = v;
  cursor[i] = v;
  if (i == NT - 1) off[NT] = E_;
  float d = 1.f + (float)cnt[i];
  float di = 1.f / sqrtf(d);
  dinv[i] = di;
  selfw[i] = di * di;
  scale[i] = 1.f;
}

__global__ void k_fill_srcp(const int* __restrict__ src, const int* __restrict__ dst,
                            int* __restrict__ cursor, int* __restrict__ srcp) {
  int e = blockIdx.x * 256 + threadIdx.x;
  if (e < E_) {
    int p = atomicAdd(&cursor[dst[e]], 1);
    srcp[p] = src[e];
  }
}

// ---- dense matmul: C[rows x 128] = (scale .* A)[rows x 128] @ W ------------
// 128x128 tile / 256 threads; 8 rows x 8 cols per thread. Thread cols are
// {4c..4c+3, 64+4c..67+4c} -> W float4 reads start at stride-4 banks = 2-way
// (free). Register double-buffer: next k-chunk prefetched during compute.
__global__ __launch_bounds__(256) void k_matmul(const float* __restrict__ A,
                                                const float* __restrict__ scale,
                                                const float* __restrict__ W,
                                                float* __restrict__ C,
                                                const int* __restrict__ kept,
                                                int kshift) {
  __shared__ float Ast[32 * AST];
  __shared__ float Ws[32 * AST];
  __shared__ int rowid[128];
  __shared__ float rsc[128];
  const int tid = threadIdx.x;
  if (tid < 128) {
    int q = blockIdx.x * 128 + tid;
    int row;
    if (kept) {
      int g = q >> kshift;
      row = kept[g * N_ + (q - (g << kshift))];
    } else {
      row = q;
    }
    rowid[tid] = row;
    rsc[tid] = scale[row];
  }
  __syncthreads();
  const int rowq = tid >> 4;   // 0..15 -> rows 8*rowq..+7
  const int colq = tid & 15;   // 0..15 -> cols {4c..4c+3, 64+4c..+3}
  float4 va[4], vw[4];
  // prefetch chunk 0
#pragma unroll
  for (int i = 0; i < 4; ++i) {
    int idx = tid + 256 * i;
    int row = idx & 127, fq = idx >> 7;
    va[i] = *(const float4*)&A[(size_t)rowid[row] * 128 + 4 * fq];
  }
#pragma unroll
  for (int i = 0; i < 4; ++i) {
    int idx = tid + 256 * i;
    int kk = idx >> 5, cf = idx & 31;
    vw[i] = *(const float4*)&W[(size_t)kk * 128 + 4 * cf];
  }
  float acc[8][8] = {};
  for (int c = 0; c < 4; ++c) {
    // store current chunk to LDS (A transposed, stride-1 lane stores = free)
#pragma unroll
    for (int i = 0; i < 4; ++i) {
      int idx = tid + 256 * i;
      int row = idx & 127, fq = idx >> 7;
      float sc = rsc[row];
      Ast[(4 * fq + 0) * AST + row] = va[i].x * sc;
      Ast[(4 * fq + 1) * AST + row] = va[i].y * sc;
      Ast[(4 * fq + 2) * AST + row] = va[i].z * sc;
      Ast[(4 * fq + 3) * AST + row] = va[i].w * sc;
    }
#pragma unroll
    for (int i = 0; i < 4; ++i) {
      int idx = tid + 256 * i;
      int kk = idx >> 5, cf = idx & 31;
      *(float4*)&Ws[kk * AST + 4 * cf] = vw[i];
    }
    __syncthreads();
    // prefetch next chunk (global latency overlapped with compute)
    if (c < 3) {
      int k0n = 32 * (c + 1);
#pragma unroll
      for (int i = 0; i < 4; ++i) {
        int idx = tid + 256 * i;
        int row = idx & 127, fq = idx >> 7;
        va[i] = *(const float4*)&A[(size_t)rowid[row] * 128 + k0n + 4 * fq];
      }
#pragma unroll
      for (int i = 0; i < 4; ++i) {
        int idx = tid + 256 * i;
        int kk = idx >> 5, cf = idx & 31;
        vw[i] = *(const float4*)&W[(size_t)(k0n + kk) * 128 + 4 * cf];
      }
    }
#pragma unroll 2
    for (int kk = 0; kk < 32; ++kk) {
      float4 a0 = *(const float4*)&Ast[kk * AST + 8 * rowq];
      float4 a1 = *(const float4*)&Ast[kk * AST + 8 * rowq + 4];
      float4 w0 = *(const float4*)&Ws[kk * AST + 4 * colq];
      float4 w1 = *(const float4*)&Ws[kk * AST + 64 + 4 * colq];
      float a[8] = {a0.x, a0.y, a0.z, a0.w, a1.x, a1.y, a1.z, a1.w};
      float w[8] = {w0.x, w0.y, w0.z, w0.w, w1.x, w1.y, w1.z, w1.w};
#pragma unroll
      for (int r = 0; r < 8; ++r)
#pragma unroll
        for (int cc = 0; cc < 8; ++cc) acc[r][cc] += a[r] * w[cc];
    }
    __syncthreads();
  }
#pragma unroll
  for (int r = 0; r < 8; ++r) {
    float* Crow = &C[(size_t)rowid[8 * rowq + r] * 128];
    *(float4*)&Crow[4 * colq] = make_float4(acc[r][0], acc[r][1], acc[r][2], acc[r][3]);
    *(float4*)&Crow[64 + 4 * colq] = make_float4(acc[r][4], acc[r][5], acc[r][6], acc[r][7]);
  }
}

// ---- feature aggregation + bias + relu + fused score matvec ---------------
__global__ __launch_bounds__(256) void k_agg(const float4* __restrict__ t4,
                                             const int* __restrict__ off,
                                             const int* __restrict__ srcp,
                                             const float* __restrict__ dinv,
                                             const float* __restrict__ selfw,
                                             const float* __restrict__ bias,
                                             const float* __restrict__ Wp,
                                             float4* __restrict__ h4,
                                             float* __restrict__ t1,
                                             const int* __restrict__ kept,
                                             int kshift) {
  int chunk = gridDim.x >> 3;
  int bs = ((blockIdx.x & 7) * chunk) + (blockIdx.x >> 3);  // XCD L2 locality
  int q = bs * 8 + (threadIdx.x >> 5);
  int node;
  if (kept) {
    int g = q >> kshift;
    node = kept[g * N_ + (q - (g << kshift))];
  } else {
    node = q;
  }
  const int lane = threadIdx.x & 31;
  const float dvi = dinv[node];
  float sw = selfw[node];
  float4 self = t4[(size_t)node * 32 + lane];
  float4 acc = make_float4(sw * self.x, sw * self.y, sw * self.z, sw * self.w);
  int s = off[node], en = off[node + 1];
  int j = s;
  for (; j + 4 <= en; j += 4) {
    int s0 = srcp[j], s1 = srcp[j + 1], s2 = srcp[j + 2], s3 = srcp[j + 3];
    float c0 = dinv[s0] * dvi, c1 = dinv[s1] * dvi;
    float c2 = dinv[s2] * dvi, c3 = dinv[s3] * dvi;
    if (c0 != 0.f) {
      float4 r0 = t4[(size_t)s0 * 32 + lane];
      acc.x += c0 * r0.x; acc.y += c0 * r0.y; acc.z += c0 * r0.z; acc.w += c0 * r0.w;
    }
    if (c1 != 0.f) {
      float4 r1 = t4[(size_t)s1 * 32 + lane];
      acc.x += c1 * r1.x; acc.y += c1 * r1.y; acc.z += c1 * r1.z; acc.w += c1 * r1.w;
    }
    if (c2 != 0.f) {
      float4 r2 = t4[(size_t)s2 * 32 + lane];
      acc.x += c2 * r2.x; acc.y += c2 * r2.y; acc.z += c2 * r2.z; acc.w += c2 * r2.w;
    }
    if (c3 != 0.f) {
      float4 r3 = t4[(size_t)s3 * 32 + lane];
      acc.x += c3 * r3.x; acc.y += c3 * r3.y; acc.z += c3 * r3.z; acc.w += c3 * r3.w;
    }
  }
  for (; j < en; ++j) {
    int s0 = srcp[j];
    float c0 = dinv[s0] * dvi;
    if (c0 != 0.f) {
      float4 r0 = t4[(size_t)s0 * 32 + lane];
      acc.x += c0 * r0.x; acc.y += c0 * r0.y; acc.z += c0 * r0.z; acc.w += c0 * r0.w;
    }
  }
  float4 b4 = ((const float4*)bias)[lane];
  acc.x = fmaxf(acc.x + b4.x, 0.f);
  acc.y = fmaxf(acc.y + b4.y, 0.f);
  acc.z = fmaxf(acc.z + b4.z, 0.f);
  acc.w = fmaxf(acc.w + b4.w, 0.f);
  h4[(size_t)node * 32 + lane] = acc;
  float4 wp = ((const float4*)Wp)[lane];
  float part = acc.x * wp.x + acc.y * wp.y + acc.z * wp.z + acc.w * wp.w;
#pragma unroll
  for (int o = 16; o > 0; o >>= 1) part += __shfl_down(part, o, 32);
  if (lane == 0) t1[node] = part;
}

// ---- fused pool + readout: score agg + radix top-k + scale + next-layer
// deg + kept list + per-graph [max|mean] readout. One block per graph.
__global__ __launch_bounds__(1024) void k_pool(const float* __restrict__ t1,
                                               const int* __restrict__ off,
                                               const int* __restrict__ srcp,
                                               float* __restrict__ dinv,
                                               float* __restrict__ selfw,
                                               const float* __restrict__ bp,
                                               float* __restrict__ scale,
                                               int* __restrict__ kept,
                                               const float4* __restrict__ h4,
                                               float* __restrict__ gout,
                                               float invk, int k) {
  __shared__ float st1[2048];       // scores in; scale after
  __shared__ float sdv[2048];
  __shared__ float skp[2048];
  __shared__ int skept[1024];
  __shared__ unsigned rephist[4096];  // 16 waves x 256 bins; reused as red[]
  __shared__ unsigned ebits[64];
  __shared__ int wsum[16];
  __shared__ unsigned bc_digit, bc_prev;
  const int g = blockIdx.x, t = threadIdx.x;
  const int base = g * N_;
  st1[t] = t1[base + t];
  st1[t + 1024] = t1[base + t + 1024];
  sdv[t] = dinv[base + t];
  sdv[t + 1024] = dinv[base + t + 1024];
  float sw[2] = {selfw[base + t], selfw[base + t + 1024]};
  if (t < 64) ebits[t] = 0u;
#pragma unroll
  for (int i = 0; i < 4; ++i) rephist[t + 1024 * i] = 0u;
  __syncthreads();
  // scores for my two nodes (edge loop over LDS; coef = dinv_s * dinv_d)
  float raw[2];
  unsigned key[2];
  float bpv = bp[0];
#pragma unroll
  for (int q = 0; q < 2; ++q) {
    int n = t + q * 1024;
    float di = sdv[n];
    float a = 0.f;
    int s = off[base + n], en = off[base + n + 1];
    for (int j = s; j < en; ++j) {
      int sl = srcp[j] - base;
      a += sdv[sl] * st1[sl];
    }
    raw[q] = sw[q] * st1[n] + di * a + bpv;
    unsigned u = __float_as_uint(raw[q]);
    u = (u & 0x80000000u) ? ~u : (u | 0x80000000u);
    u = ~u;  // descending
    if (di <= 0.f) u = 0xFFFFFFFFu;
    key[q] = u;
  }
  // radix-select: k-th smallest key = k-th largest score
  unsigned prefix = 0u, rem = (unsigned)k;
  const int wv = t >> 6;
  for (int shift = 24; shift >= 0; shift -= 8) {
    unsigned mask = (shift == 24) ? 0u : (0xFFFFFFFFu << (shift + 8));
#pragma unroll
    for (int q = 0; q < 2; ++q)
      if ((key[q] & mask) == prefix)
        atomicAdd(&rephist[(wv << 8) + ((key[q] >> shift) & 255u)], 1u);
    __syncthreads();
    unsigned binv = 0u, v = 0u;
    if (t < 256) {
#pragma unroll
      for (int w = 0; w < 16; ++w) binv += rephist[(w << 8) + t];
      v = binv;
#pragma unroll
      for (int o = 1; o < 64; o <<= 1) {
        unsigned nv = __shfl_up(v, o);
        if ((t & 63) >= o) v += nv;
      }
      if ((t & 63) == 63) wsum[t >> 6] = (int)v;
    }
    __syncthreads();
    if (t < 256) {
      unsigned pre = 0u;
      int w4 = t >> 6;
      for (int u = 0; u < w4; ++u) pre += (unsigned)wsum[u];
      unsigned inc = v + pre, exc = inc - binv;
      if (inc >= rem && exc < rem) { bc_digit = (unsigned)t; bc_prev = exc; }
    }
    __syncthreads();
    if (shift > 0) {
#pragma unroll
      for (int i = 0; i < 4; ++i) rephist[t + 1024 * i] = 0u;
    }
    __syncthreads();
    prefix |= bc_digit << shift;
    rem -= bc_prev;
  }
  const unsigned Tkey = prefix;
  const int need = (int)rem;  // ties to keep, lowest index first
#pragma unroll
  for (int q = 0; q < 2; ++q) {
    int n = t + q * 1024;
    if (key[q] == Tkey) atomicOr(&ebits[n >> 5], 1u << (n & 31));
  }
  __syncthreads();
#pragma unroll
  for (int q = 0; q < 2; ++q) {
    int n = t + q * 1024;
    float kp;
    if (key[q] < Tkey) {
      kp = 1.f;
    } else if (key[q] == Tkey) {
      int w = n >> 5;
      int rank = __popc(ebits[w] & ((1u << (n & 31)) - 1u));
      for (int u = 0; u < w; ++u) rank += __popc(ebits[u]);
      kp = (rank < need) ? 1.f : 0.f;
    } else {
      kp = 0.f;
    }
    skp[n] = kp;
    float sc = kp * tanhf(raw[q]);
    scale[base + n] = sc;
    st1[n] = sc;  // scale now lives in LDS for the readout phase
  }
  __syncthreads();
  // compacted kept list (ascending node index) -> global + LDS
  {
    int lane = t & 63, w = t >> 6;
    int a0 = (int)skp[2 * t], a1 = (int)skp[2 * t + 1];
    int ps = a0 + a1;
    int v = ps;
#pragma unroll
    for (int o = 1; o < 64; o <<= 1) {
      int nv = __shfl_up(v, o);
      if (lane >= o) v += nv;
    }
    if (lane == 63) wsum[w] = v;
    __syncthreads();
    if (t == 0) {
      int accv = 0;
      for (int i = 0; i < 16; ++i) { int tmp = wsum[i]; wsum[i] = accv; accv += tmp; }
    }
    __syncthreads();
    int excl = wsum[w] + v - ps;
    if (a0) { kept[base + excl] = base + 2 * t; skept[excl] = base + 2 * t; }
    if (a1) { kept[base + excl + a0] = base + 2 * t + 1; skept[excl + a0] = base + 2 * t + 1; }
  }
  // next-layer deg/dinv/selfw from new nmask (in LDS)
#pragma unroll
  for (int q = 0; q < 2; ++q) {
    int n = t + q * 1024;
    float nm = skp[n];
    float d = nm;
    int s = off[base + n], en = off[base + n + 1];
    for (int j = s; j < en; ++j) d += skp[srcp[j] - base];
    float di = (nm > 0.f) ? (1.f / sqrtf(d)) : 0.f;
    dinv[base + n] = di;
    selfw[base + n] = di * di * nm;
  }
  __syncthreads();
  // readout over kept list: [max, mean] of scale.*h
  const int lane = t & 31, ng = t >> 5;
  float4 mx = make_float4(-INFINITY, -INFINITY, -INFINITY, -INFINITY);
  float4 sm = make_float4(0.f, 0.f, 0.f, 0.f);
  for (int i = ng; i < k; i += 32) {
    int node = skept[i];
    float sc = st1[node - base];
    float4 v = h4[(size_t)node * 32 + lane];
    v.x *= sc; v.y *= sc; v.z *= sc; v.w *= sc;
    mx.x = fmaxf(mx.x, v.x); mx.y = fmaxf(mx.y, v.y);
    mx.z = fmaxf(mx.z, v.z); mx.w = fmaxf(mx.w, v.w);
    sm.x += v.x; sm.y += v.y; sm.z += v.z; sm.w += v.w;
  }
  float4* red = (float4*)rephist;  // 1024 float4 = 16KB, radix is done with it
  for (int d = 16; d >= 1; d >>= 1) {
    if (ng >= d && ng < 2 * d) {
      red[(ng - d) * 32 + lane] = mx;
      red[512 + (ng - d) * 32 + lane] = sm;
    }
    __syncthreads();
    if (ng < d) {
      float4 omx = red[ng * 32 + lane];
      float4 osm = red[512 + ng * 32 + lane];
      mx.x = fmaxf(mx.x, omx.x); mx.y = fmaxf(mx.y, omx.y);
      mx.z = fmaxf(mx.z, omx.z); mx.w = fmaxf(mx.w, omx.w);
      sm.x += osm.x; sm.y += osm.y; sm.z += osm.z; sm.w += osm.w;
    }
    __syncthreads();
  }
  if (ng == 0) {
    gout[g * 256 + 4 * lane + 0] = mx.x;
    gout[g * 256 + 4 * lane + 1] = mx.y;
    gout[g * 256 + 4 * lane + 2] = mx.z;
    gout[g * 256 + 4 * lane + 3] = mx.w;
    gout[g * 256 + 128 + 4 * lane + 0] = sm.x * invk;
    gout[g * 256 + 128 + 4 * lane + 1] = sm.y * invk;
    gout[g * 256 + 128 + 4 * lane + 2] = sm.z * invk;
    gout[g * 256 + 128 + 4 * lane + 3] = sm.w * invk;
  }
}

// ---- MLP head + log_softmax ------------------------------------------------
__global__ __launch_bounds__(128) void k_mlp(const float* __restrict__ g0,
                                             const float* __restrict__ g1,
                                             const float* __restrict__ g2,
                                             const float* __restrict__ W1,
                                             const float* __restrict__ b1,
                                             const float* __restrict__ W2,
                                             const float* __restrict__ b2,
                                             const float* __restrict__ W3,
                                             const float* __restrict__ b3,
                                             float* __restrict__ out) {
  __shared__ float gr[256], o1[128], o2[64], o3[NCLS];
  int g = blockIdx.x, t = threadIdx.x;
  gr[t] = g0[g * 256 + t] + g1[g * 256 + t] + g2[g * 256 + t];
  gr[t + 128] = g0[g * 256 + 128 + t] + g1[g * 256 + 128 + t] + g2[g * 256 + 128 + t];
  __syncthreads();
  float a = b1[t];
  for (int kk = 0; kk < 256; ++kk) a += gr[kk] * W1[kk * 128 + t];
  o1[t] = fmaxf(a, 0.f);
  __syncthreads();
  if (t < 64) {
    float a2 = b2[t];
    for (int kk = 0; kk < 128; ++kk) a2 += o1[kk] * W2[kk * 64 + t];
    o2[t] = fmaxf(a2, 0.f);
  }
  __syncthreads();
  if (t < NCLS) {
    float a3 = b3[t];
    for (int kk = 0; kk < 64; ++kk) a3 += o2[kk] * W3[kk * NCLS + t];
    o3[t] = a3;
  }
  __syncthreads();
  if (t == 0) {
    float m = -INFINITY;
    for (int c = 0; c < NCLS; ++c) m = fmaxf(m, o3[c]);
    float sum = 0.f;
    for (int c = 0; c < NCLS; ++c) sum += expf(o3[c] - m);
    float lse = logf(sum);
    for (int c = 0; c < NCLS; ++c) out[g * NCLS + c] = o3[c] - m - lse;
  }
}

}  // namespace

extern "C" void kernel_launch(void* const* d_in, const int* in_sizes, int n_in,
                              void* d_out, int out_size, void* d_ws, size_t ws_size,
                              hipStream_t stream) {
  const float* x = (const float*)d_in[0];
  const int* ei = (const int*)d_in[1];
  const int* src = ei;
  const int* dst = ei + E_;
  const float* Wl[3]  = {(const float*)d_in[3], (const float*)d_in[7], (const float*)d_in[11]};
  const float* bl[3]  = {(const float*)d_in[4], (const float*)d_in[8], (const float*)d_in[12]};
  const float* Wpl[3] = {(const float*)d_in[5], (const float*)d_in[9], (const float*)d_in[13]};
  const float* bpl[3] = {(const float*)d_in[6], (const float*)d_in[10], (const float*)d_in[14]};
  const float* l1W = (const float*)d_in[15];
  const float* l1b = (const float*)d_in[16];
  const float* l2W = (const float*)d_in[17];
  const float* l2b = (const float*)d_in[18];
  const float* l3W = (const float*)d_in[19];
  const float* l3b = (const float*)d_in[20];

  char* p = (char*)d_ws;
  auto alloc = [&](size_t bytes) -> void* {
    void* r = (void*)p;
    p += (bytes + 255) & ~size_t(255);
    return r;
  };
  float* h      = (float*)alloc((size_t)NT * 128 * 4);
  float* t      = (float*)alloc((size_t)NT * 128 * 4);
  float* dinv   = (float*)alloc(NT * 4);
  float* selfw  = (float*)alloc(NT * 4);
  float* t1     = (float*)alloc(NT * 4);
  float* scale  = (float*)alloc(NT * 4);
  int*   srcp   = (int*)alloc(E_ * 4);
  int*   off    = (int*)alloc((NT + 1) * 4);
  int*   cnt    = (int*)alloc(NT * 4);
  int*   cursor = (int*)alloc(NT * 4);
  int*   bsum   = (int*)alloc(256 * 4);
  int*   kept0  = (int*)alloc(NT * 4);
  int*   kept1  = (int*)alloc(NT * 4);
  int*   kept2  = (int*)alloc(NT * 4);
  float* gout0  = (float*)alloc(B_ * 256 * 4);
  float* gout1  = (float*)alloc(B_ * 256 * 4);
  float* gout2  = (float*)alloc(B_ * 256 * 4);

  int* keptL[3] = {kept0, kept1, kept2};
  float* goutL[3] = {gout0, gout1, gout2};
  const int K[3] = {1024, 512, 256};
  const int KSH[3] = {10, 9, 8};

  hipMemsetAsync(cnt, 0, NT * 4, stream);

  k_count<<<E_ / 256, 256, 0, stream>>>(dst, cnt);
  k_scan1<<<256, 256, 0, stream>>>(cnt, off, bsum);
  k_scan3<<<256, 256, 0, stream>>>(off, bsum, cnt, cursor, dinv, selfw, scale);
  k_fill_srcp<<<E_ / 256, 256, 0, stream>>>(src, dst, cursor, srcp);

  const float* inF = x;
  for (int l = 0; l < 3; ++l) {
    const int* inKept = (l == 0) ? nullptr : keptL[l - 1];
    int inKsh = (l == 0) ? 11 : KSH[l - 1];
    int nrows = (l == 0) ? NT : B_ * K[l - 1];
    k_matmul<<<nrows / 128, 256, 0, stream>>>(inF, scale, Wl[l], t, inKept, inKsh);
    k_agg<<<nrows / 8, 256, 0, stream>>>((const float4*)t, off, srcp, dinv, selfw,
                                         bl[l], Wpl[l], (float4*)h, t1, inKept, inKsh);
    k_pool<<<B_, 1024, 0, stream>>>(t1, off, srcp, dinv, selfw, bpl[l], scale,
                                    keptL[l], (const float4*)h, goutL[l],
                                    1.f / (float)K[l], K[l]);
    inF = h;
  }
  k_mlp<<<B_, 128, 0, stream>>>(gout0, gout1, gout2,
                                l1W, l1b, l2W, l2b, l3W, l3b, (float*)d_out);
}

// Round 8
// 367.200 us; speedup vs baseline: 1.0931x; 1.0931x over previous
//
#include <hip/hip_runtime.h>
#include <math.h>

// ---------------------------------------------------------------------------
// SAGPool GNN forward: 3x [GCNConv -> SAGPool(top-k) -> readout] + MLP head.
// B=32 graphs x N=2048 nodes; E=524288; 128 feats; K = 1024/512/256.
// R8 changes vs R7 (401us; matmul conflict-free but flat -> latency; FETCH
// shows cross-XCD L2 misses between producer/consumer kernels):
//   - graph->XCD = g%8 relabeling in ALL kernels (assumes blockIdx%8=XCD,
//     same heuristic as prior swizzle): graph's t/h stay in one XCD L2.
//   - scale fold: (D_s H)W = D_s(HW). Matmul is pure A@W; pool emits
//     ds=dinv*scale, sws=dinv^2*scale; agg coef=ds[s]*dinv[d], self=sws.
//     scale/selfw arrays deleted (selfw==dinv^2).
//   - matmul: LDS double-buffer, ONE barrier per k-chunk, register prefetch.
// ---------------------------------------------------------------------------

namespace {

constexpr int B_  = 32;
constexpr int N_  = 2048;
constexpr int NT  = B_ * N_;        // 65536
constexpr int E_  = B_ * 16384;     // 524288
constexpr int NCLS = 10;
constexpr int AST = 132;            // A-tile LDS row stride (128 + 4 pad)

// blockIdx -> logical block, grouping graphs g%8 per XCD (blockIdx%8=XCD).
// grid = 32*bpg blocks, bpg = blocks per graph = 1<<bpgsh.
__device__ __forceinline__ int relabel(int bpgsh) {
  int x = blockIdx.x & 7, slot = blockIdx.x >> 3;
  int g = x + 8 * (slot >> bpgsh);
  return (g << bpgsh) + (slot & ((1 << bpgsh) - 1));
}

// ---- CSR build -------------------------------------------------------------
__global__ void k_count(const int* __restrict__ dst, int* __restrict__ cnt) {
  int e = blockIdx.x * 256 + threadIdx.x;
  if (e < E_) atomicAdd(&cnt[dst[e]], 1);
}

__global__ void k_scan1(const int* __restrict__ cnt, int* __restrict__ off,
                        int* __restrict__ bsum) {
  __shared__ int s[256];
  int t = threadIdx.x;
  int i = blockIdx.x * 256 + t;
  int v = cnt[i];
  s[t] = v;
  __syncthreads();
  for (int d = 1; d < 256; d <<= 1) {
    int add = (t >= d) ? s[t - d] : 0;
    __syncthreads();
    s[t] += add;
    __syncthreads();
  }
  off[i] = s[t] - v;  // exclusive within block
  if (t == 255) bsum[blockIdx.x] = s[255];
}

// adds bsum prefix, writes cursor; layer-0 dinv/ds/sws (scale=1).
__global__ void k_scan3(int* __restrict__ off, const int* __restrict__ bsum,
                        const int* __restrict__ cnt, int* __restrict__ cursor,
                        float* __restrict__ dinv, float* __restrict__ ds,
                        float* __restrict__ sws) {
  __shared__ int sb[256];
  int t = threadIdx.x;
  sb[t] = bsum[t];
  __syncthreads();
  for (int d = 1; d < 256; d <<= 1) {
    int add = (t >= d) ? sb[t - d] : 0;
    __syncthreads();
    sb[t] += add;
    __syncthreads();
  }
  int prefix = (blockIdx.x == 0) ? 0 : sb[blockIdx.x - 1];
  int i = blockIdx.x * 256 + t;
  int v = off[i] + prefix;
  off[i] = v;
  cursor[i] = v;
  if (i == NT - 1) off[NT] = E_;
  float d = 1.f + (float)cnt[i];
  float di = 1.f / sqrtf(d);
  dinv[i] = di;
  ds[i] = di;        // dinv * scale(=1)
  sws[i] = di * di;  // dinv^2 * scale(=1)
}

__global__ void k_fill_srcp(const int* __restrict__ src, const int* __restrict__ dst,
                            int* __restrict__ cursor, int* __restrict__ srcp) {
  int e = blockIdx.x * 256 + threadIdx.x;
  if (e < E_) {
    int p = atomicAdd(&cursor[dst[e]], 1);
    srcp[p] = src[e];
  }
}

// ---- dense matmul: C[rows x 128] = A[rows x 128] @ W (no scale) ------------
// 128x128 tile / 256 threads; 8x8 per thread; LDS double-buffer, one barrier
// per k-chunk; cols {4c,64+4c} -> all LDS reads <=2-way (free).
__global__ __launch_bounds__(256) void k_matmul(const float* __restrict__ A,
                                                const float* __restrict__ W,
                                                float* __restrict__ C,
                                                const int* __restrict__ kept,
                                                int kshift, int bpgsh) {
  __shared__ float Ast[2][32 * AST];
  __shared__ float Ws[2][32 * 128];
  __shared__ int rowid[128];
  const int tid = threadIdx.x;
  const int tile = relabel(bpgsh);
  if (kept) {
    if (tid < 128) {
      int q = tile * 128 + tid;
      int g = q >> kshift;
      rowid[tid] = kept[g * N_ + (q - (g << kshift))];
    }
    __syncthreads();
  }
  const int rowq = tid >> 4;   // 0..15 -> rows 8*rowq..+7
  const int colq = tid & 15;   // cols {4c..4c+3, 64+4c..+3}
  float4 va[4], vw[4];
  // prefetch chunk 0
#pragma unroll
  for (int i = 0; i < 4; ++i) {
    int idx = tid + 256 * i;
    int row = idx & 127, fq = idx >> 7;
    int gr = kept ? rowid[row] : tile * 128 + row;
    va[i] = *(const float4*)&A[(size_t)gr * 128 + 4 * fq];
  }
#pragma unroll
  for (int i = 0; i < 4; ++i) {
    int idx = tid + 256 * i;
    int kk = idx >> 5, cf = idx & 31;
    vw[i] = *(const float4*)&W[(size_t)kk * 128 + 4 * cf];
  }
  // store chunk 0 -> buf 0
#pragma unroll
  for (int i = 0; i < 4; ++i) {
    int idx = tid + 256 * i;
    int row = idx & 127, fq = idx >> 7;
    Ast[0][(4 * fq + 0) * AST + row] = va[i].x;
    Ast[0][(4 * fq + 1) * AST + row] = va[i].y;
    Ast[0][(4 * fq + 2) * AST + row] = va[i].z;
    Ast[0][(4 * fq + 3) * AST + row] = va[i].w;
  }
#pragma unroll
  for (int i = 0; i < 4; ++i) {
    int idx = tid + 256 * i;
    int kk = idx >> 5, cf = idx & 31;
    *(float4*)&Ws[0][kk * 128 + 4 * cf] = vw[i];
  }
  __syncthreads();
  float acc[8][8] = {};
  for (int c = 0; c < 4; ++c) {
    int cur = c & 1;
    if (c < 3) {  // prefetch next chunk into regs (in flight during compute)
      int k0n = 32 * (c + 1);
#pragma unroll
      for (int i = 0; i < 4; ++i) {
        int idx = tid + 256 * i;
        int row = idx & 127, fq = idx >> 7;
        int gr = kept ? rowid[row] : tile * 128 + row;
        va[i] = *(const float4*)&A[(size_t)gr * 128 + k0n + 4 * fq];
      }
#pragma unroll
      for (int i = 0; i < 4; ++i) {
        int idx = tid + 256 * i;
        int kk = idx >> 5, cf = idx & 31;
        vw[i] = *(const float4*)&W[(size_t)(k0n + kk) * 128 + 4 * cf];
      }
    }
#pragma unroll 2
    for (int kk = 0; kk < 32; ++kk) {
      float4 a0 = *(const float4*)&Ast[cur][kk * AST + 8 * rowq];
      float4 a1 = *(const float4*)&Ast[cur][kk * AST + 8 * rowq + 4];
      float4 w0 = *(const float4*)&Ws[cur][kk * 128 + 4 * colq];
      float4 w1 = *(const float4*)&Ws[cur][kk * 128 + 64 + 4 * colq];
      float a[8] = {a0.x, a0.y, a0.z, a0.w, a1.x, a1.y, a1.z, a1.w};
      float w[8] = {w0.x, w0.y, w0.z, w0.w, w1.x, w1.y, w1.z, w1.w};
#pragma unroll
      for (int r = 0; r < 8; ++r)
#pragma unroll
        for (int cc = 0; cc < 8; ++cc) acc[r][cc] += a[r] * w[cc];
    }
    if (c < 3) {  // store prefetched chunk into other buffer; ONE barrier
      int nxt = cur ^ 1;
#pragma unroll
      for (int i = 0; i < 4; ++i) {
        int idx = tid + 256 * i;
        int row = idx & 127, fq = idx >> 7;
        Ast[nxt][(4 * fq + 0) * AST + row] = va[i].x;
        Ast[nxt][(4 * fq + 1) * AST + row] = va[i].y;
        Ast[nxt][(4 * fq + 2) * AST + row] = va[i].z;
        Ast[nxt][(4 * fq + 3) * AST + row] = va[i].w;
      }
#pragma unroll
      for (int i = 0; i < 4; ++i) {
        int idx = tid + 256 * i;
        int kk = idx >> 5, cf = idx & 31;
        *(float4*)&Ws[nxt][kk * 128 + 4 * cf] = vw[i];
      }
      __syncthreads();
    }
  }
#pragma unroll
  for (int r = 0; r < 8; ++r) {
    int gr = kept ? rowid[8 * rowq + r] : tile * 128 + 8 * rowq + r;
    float* Crow = &C[(size_t)gr * 128];
    *(float4*)&Crow[4 * colq] = make_float4(acc[r][0], acc[r][1], acc[r][2], acc[r][3]);
    *(float4*)&Crow[64 + 4 * colq] = make_float4(acc[r][4], acc[r][5], acc[r][6], acc[r][7]);
  }
}

// ---- feature aggregation + bias + relu + fused score matvec ---------------
// coef = ds[src] * dinv[node] (scale folded into ds); self = sws[node].
__global__ __launch_bounds__(256) void k_agg(const float4* __restrict__ t4,
                                             const int* __restrict__ off,
                                             const int* __restrict__ srcp,
                                             const float* __restrict__ dinv,
                                             const float* __restrict__ ds,
                                             const float* __restrict__ sws,
                                             const float* __restrict__ bias,
                                             const float* __restrict__ Wp,
                                             float4* __restrict__ h4,
                                             float* __restrict__ t1,
                                             const int* __restrict__ kept,
                                             int kshift, int bpgsh) {
  int q = relabel(bpgsh) * 8 + (threadIdx.x >> 5);
  int node;
  if (kept) {
    int g = q >> kshift;
    node = kept[g * N_ + (q - (g << kshift))];
  } else {
    node = q;
  }
  const int lane = threadIdx.x & 31;
  const float dvi = dinv[node];
  float sw = sws[node];
  float4 self = t4[(size_t)node * 32 + lane];
  float4 acc = make_float4(sw * self.x, sw * self.y, sw * self.z, sw * self.w);
  int s = off[node], en = off[node + 1];
  int j = s;
  for (; j + 4 <= en; j += 4) {
    int s0 = srcp[j], s1 = srcp[j + 1], s2 = srcp[j + 2], s3 = srcp[j + 3];
    float c0 = ds[s0] * dvi, c1 = ds[s1] * dvi;
    float c2 = ds[s2] * dvi, c3 = ds[s3] * dvi;
    if (c0 != 0.f) {
      float4 r0 = t4[(size_t)s0 * 32 + lane];
      acc.x += c0 * r0.x; acc.y += c0 * r0.y; acc.z += c0 * r0.z; acc.w += c0 * r0.w;
    }
    if (c1 != 0.f) {
      float4 r1 = t4[(size_t)s1 * 32 + lane];
      acc.x += c1 * r1.x; acc.y += c1 * r1.y; acc.z += c1 * r1.z; acc.w += c1 * r1.w;
    }
    if (c2 != 0.f) {
      float4 r2 = t4[(size_t)s2 * 32 + lane];
      acc.x += c2 * r2.x; acc.y += c2 * r2.y; acc.z += c2 * r2.z; acc.w += c2 * r2.w;
    }
    if (c3 != 0.f) {
      float4 r3 = t4[(size_t)s3 * 32 + lane];
      acc.x += c3 * r3.x; acc.y += c3 * r3.y; acc.z += c3 * r3.z; acc.w += c3 * r3.w;
    }
  }
  for (; j < en; ++j) {
    int s0 = srcp[j];
    float c0 = ds[s0] * dvi;
    if (c0 != 0.f) {
      float4 r0 = t4[(size_t)s0 * 32 + lane];
      acc.x += c0 * r0.x; acc.y += c0 * r0.y; acc.z += c0 * r0.z; acc.w += c0 * r0.w;
    }
  }
  float4 b4 = ((const float4*)bias)[lane];
  acc.x = fmaxf(acc.x + b4.x, 0.f);
  acc.y = fmaxf(acc.y + b4.y, 0.f);
  acc.z = fmaxf(acc.z + b4.z, 0.f);
  acc.w = fmaxf(acc.w + b4.w, 0.f);
  h4[(size_t)node * 32 + lane] = acc;
  float4 wp = ((const float4*)Wp)[lane];
  float part = acc.x * wp.x + acc.y * wp.y + acc.z * wp.z + acc.w * wp.w;
#pragma unroll
  for (int o = 16; o > 0; o >>= 1) part += __shfl_down(part, o, 32);
  if (lane == 0) t1[node] = part;
}

// ---- fused pool + readout (one block per graph, relabeled g%8 per XCD) ----
__global__ __launch_bounds__(1024) void k_pool(const float* __restrict__ t1,
                                               const int* __restrict__ off,
                                               const int* __restrict__ srcp,
                                               float* __restrict__ dinv,
                                               float* __restrict__ ds,
                                               float* __restrict__ sws,
                                               const float* __restrict__ bp,
                                               int* __restrict__ kept,
                                               const float4* __restrict__ h4,
                                               float* __restrict__ gout,
                                               float invk, int k) {
  __shared__ float st1[2048];       // t1 in; scale after selection
  __shared__ float sdv[2048];
  __shared__ float skp[2048];
  __shared__ int skept[1024];
  __shared__ unsigned rephist[4096];  // 16 waves x 256 bins; reused as red[]
  __shared__ unsigned ebits[64];
  __shared__ int wsum[16];
  __shared__ unsigned bc_digit, bc_prev;
  const int g = (blockIdx.x & 7) + 8 * (blockIdx.x >> 3);
  const int t = threadIdx.x;
  const int base = g * N_;
  st1[t] = t1[base + t];
  st1[t + 1024] = t1[base + t + 1024];
  sdv[t] = dinv[base + t];
  sdv[t + 1024] = dinv[base + t + 1024];
  if (t < 64) ebits[t] = 0u;
#pragma unroll
  for (int i = 0; i < 4; ++i) rephist[t + 1024 * i] = 0u;
  __syncthreads();
  float raw[2];
  unsigned key[2];
  float bpv = bp[0];
#pragma unroll
  for (int q = 0; q < 2; ++q) {
    int n = t + q * 1024;
    float di = sdv[n];
    float a = 0.f;
    int s = off[base + n], en = off[base + n + 1];
    for (int j = s; j < en; ++j) {
      int sl = srcp[j] - base;
      a += sdv[sl] * st1[sl];
    }
    raw[q] = di * di * st1[n] + di * a + bpv;  // selfw == dinv^2
    unsigned u = __float_as_uint(raw[q]);
    u = (u & 0x80000000u) ? ~u : (u | 0x80000000u);
    u = ~u;  // descending
    if (di <= 0.f) u = 0xFFFFFFFFu;
    key[q] = u;
  }
  // radix-select k-th largest score
  unsigned prefix = 0u, rem = (unsigned)k;
  const int wv = t >> 6;
  for (int shift = 24; shift >= 0; shift -= 8) {
    unsigned mask = (shift == 24) ? 0u : (0xFFFFFFFFu << (shift + 8));
#pragma unroll
    for (int q = 0; q < 2; ++q)
      if ((key[q] & mask) == prefix)
        atomicAdd(&rephist[(wv << 8) + ((key[q] >> shift) & 255u)], 1u);
    __syncthreads();
    unsigned binv = 0u, v = 0u;
    if (t < 256) {
#pragma unroll
      for (int w = 0; w < 16; ++w) binv += rephist[(w << 8) + t];
      v = binv;
#pragma unroll
      for (int o = 1; o < 64; o <<= 1) {
        unsigned nv = __shfl_up(v, o);
        if ((t & 63) >= o) v += nv;
      }
      if ((t & 63) == 63) wsum[t >> 6] = (int)v;
    }
    __syncthreads();
    if (t < 256) {
      unsigned pre = 0u;
      int w4 = t >> 6;
      for (int u = 0; u < w4; ++u) pre += (unsigned)wsum[u];
      unsigned inc = v + pre, exc = inc - binv;
      if (inc >= rem && exc < rem) { bc_digit = (unsigned)t; bc_prev = exc; }
    }
    __syncthreads();
    if (shift > 0) {
#pragma unroll
      for (int i = 0; i < 4; ++i) rephist[t + 1024 * i] = 0u;
    }
    __syncthreads();
    prefix |= bc_digit << shift;
    rem -= bc_prev;
  }
  const unsigned Tkey = prefix;
  const int need = (int)rem;  // ties, lowest index first
#pragma unroll
  for (int q = 0; q < 2; ++q) {
    int n = t + q * 1024;
    if (key[q] == Tkey) atomicOr(&ebits[n >> 5], 1u << (n & 31));
  }
  __syncthreads();
#pragma unroll
  for (int q = 0; q < 2; ++q) {
    int n = t + q * 1024;
    float kp;
    if (key[q] < Tkey) {
      kp = 1.f;
    } else if (key[q] == Tkey) {
      int w = n >> 5;
      int rank = __popc(ebits[w] & ((1u << (n & 31)) - 1u));
      for (int u = 0; u < w; ++u) rank += __popc(ebits[u]);
      kp = (rank < need) ? 1.f : 0.f;
    } else {
      kp = 0.f;
    }
    skp[n] = kp;
    st1[n] = kp * tanhf(raw[q]);  // scale, kept in LDS
  }
  __syncthreads();
  // compacted kept list -> global + LDS
  {
    int lane = t & 63, w = t >> 6;
    int a0 = (int)skp[2 * t], a1 = (int)skp[2 * t + 1];
    int ps = a0 + a1;
    int v = ps;
#pragma unroll
    for (int o = 1; o < 64; o <<= 1) {
      int nv = __shfl_up(v, o);
      if (lane >= o) v += nv;
    }
    if (lane == 63) wsum[w] = v;
    __syncthreads();
    if (t == 0) {
      int accv = 0;
      for (int i = 0; i < 16; ++i) { int tmp = wsum[i]; wsum[i] = accv; accv += tmp; }
    }
    __syncthreads();
    int excl = wsum[w] + v - ps;
    if (a0) { kept[base + excl] = base + 2 * t; skept[excl] = base + 2 * t; }
    if (a1) { kept[base + excl + a0] = base + 2 * t + 1; skept[excl + a0] = base + 2 * t + 1; }
  }
  // next-layer dinv/ds/sws from new nmask (in LDS)
#pragma unroll
  for (int q = 0; q < 2; ++q) {
    int n = t + q * 1024;
    float nm = skp[n];
    float d = nm;
    int s = off[base + n], en = off[base + n + 1];
    for (int j = s; j < en; ++j) d += skp[srcp[j] - base];
    float di = (nm > 0.f) ? (1.f / sqrtf(d)) : 0.f;
    float sc = st1[n];
    dinv[base + n] = di;
    ds[base + n] = di * sc;
    sws[base + n] = di * di * sc;
  }
  __syncthreads();
  // readout over kept list: [max, mean] of scale.*h
  const int lane = t & 31, ng = t >> 5;
  float4 mx = make_float4(-INFINITY, -INFINITY, -INFINITY, -INFINITY);
  float4 sm = make_float4(0.f, 0.f, 0.f, 0.f);
  for (int i = ng; i < k; i += 32) {
    int node = skept[i];
    float sc = st1[node - base];
    float4 v = h4[(size_t)node * 32 + lane];
    v.x *= sc; v.y *= sc; v.z *= sc; v.w *= sc;
    mx.x = fmaxf(mx.x, v.x); mx.y = fmaxf(mx.y, v.y);
    mx.z = fmaxf(mx.z, v.z); mx.w = fmaxf(mx.w, v.w);
    sm.x += v.x; sm.y += v.y; sm.z += v.z; sm.w += v.w;
  }
  float4* red = (float4*)rephist;  // 16KB, radix done with it
  for (int d = 16; d >= 1; d >>= 1) {
    if (ng >= d && ng < 2 * d) {
      red[(ng - d) * 32 + lane] = mx;
      red[512 + (ng - d) * 32 + lane] = sm;
    }
    __syncthreads();
    if (ng < d) {
      float4 omx = red[ng * 32 + lane];
      float4 osm = red[512 + ng * 32 + lane];
      mx.x = fmaxf(mx.x, omx.x); mx.y = fmaxf(mx.y, omx.y);
      mx.z = fmaxf(mx.z, omx.z); mx.w = fmaxf(mx.w, omx.w);
      sm.x += osm.x; sm.y += osm.y; sm.z += osm.z; sm.w += osm.w;
    }
    __syncthreads();
  }
  if (ng == 0) {
    gout[g * 256 + 4 * lane + 0] = mx.x;
    gout[g * 256 + 4 * lane + 1] = mx.y;
    gout[g * 256 + 4 * lane + 2] = mx.z;
    gout[g * 256 + 4 * lane + 3] = mx.w;
    gout[g * 256 + 128 + 4 * lane + 0] = sm.x * invk;
    gout[g * 256 + 128 + 4 * lane + 1] = sm.y * invk;
    gout[g * 256 + 128 + 4 * lane + 2] = sm.z * invk;
    gout[g * 256 + 128 + 4 * lane + 3] = sm.w * invk;
  }
}

// ---- MLP head + log_softmax ------------------------------------------------
__global__ __launch_bounds__(128) void k_mlp(const float* __restrict__ g0,
                                             const float* __restrict__ g1,
                                             const float* __restrict__ g2,
                                             const float* __restrict__ W1,
                                             const float* __restrict__ b1,
                                             const float* __restrict__ W2,
                                             const float* __restrict__ b2,
                                             const float* __restrict__ W3,
                                             const float* __restrict__ b3,
                                             float* __restrict__ out) {
  __shared__ float gr[256], o1[128], o2[64], o3[NCLS];
  int g = blockIdx.x, t = threadIdx.x;
  gr[t] = g0[g * 256 + t] + g1[g * 256 + t] + g2[g * 256 + t];
  gr[t + 128] = g0[g * 256 + 128 + t] + g1[g * 256 + 128 + t] + g2[g * 256 + 128 + t];
  __syncthreads();
  float a = b1[t];
  for (int kk = 0; kk < 256; ++kk) a += gr[kk] * W1[kk * 128 + t];
  o1[t] = fmaxf(a, 0.f);
  __syncthreads();
  if (t < 64) {
    float a2 = b2[t];
    for (int kk = 0; kk < 128; ++kk) a2 += o1[kk] * W2[kk * 64 + t];
    o2[t] = fmaxf(a2, 0.f);
  }
  __syncthreads();
  if (t < NCLS) {
    float a3 = b3[t];
    for (int kk = 0; kk < 64; ++kk) a3 += o2[kk] * W3[kk * NCLS + t];
    o3[t] = a3;
  }
  __syncthreads();
  if (t == 0) {
    float m = -INFINITY;
    for (int c = 0; c < NCLS; ++c) m = fmaxf(m, o3[c]);
    float sum = 0.f;
    for (int c = 0; c < NCLS; ++c) sum += expf(o3[c] - m);
    float lse = logf(sum);
    for (int c = 0; c < NCLS; ++c) out[g * NCLS + c] = o3[c] - m - lse;
  }
}

}  // namespace

extern "C" void kernel_launch(void* const* d_in, const int* in_sizes, int n_in,
                              void* d_out, int out_size, void* d_ws, size_t ws_size,
                              hipStream_t stream) {
  const float* x = (const float*)d_in[0];
  const int* ei = (const int*)d_in[1];
  const int* src = ei;
  const int* dst = ei + E_;
  const float* Wl[3]  = {(const float*)d_in[3], (const float*)d_in[7], (const float*)d_in[11]};
  const float* bl[3]  = {(const float*)d_in[4], (const float*)d_in[8], (const float*)d_in[12]};
  const float* Wpl[3] = {(const float*)d_in[5], (const float*)d_in[9], (const float*)d_in[13]};
  const float* bpl[3] = {(const float*)d_in[6], (const float*)d_in[10], (const float*)d_in[14]};
  const float* l1W = (const float*)d_in[15];
  const float* l1b = (const float*)d_in[16];
  const float* l2W = (const float*)d_in[17];
  const float* l2b = (const float*)d_in[18];
  const float* l3W = (const float*)d_in[19];
  const float* l3b = (const float*)d_in[20];

  char* p = (char*)d_ws;
  auto alloc = [&](size_t bytes) -> void* {
    void* r = (void*)p;
    p += (bytes + 255) & ~size_t(255);
    return r;
  };
  float* h      = (float*)alloc((size_t)NT * 128 * 4);
  float* t      = (float*)alloc((size_t)NT * 128 * 4);
  float* dinv   = (float*)alloc(NT * 4);
  float* ds     = (float*)alloc(NT * 4);
  float* sws    = (float*)alloc(NT * 4);
  float* t1     = (float*)alloc(NT * 4);
  int*   srcp   = (int*)alloc(E_ * 4);
  int*   off    = (int*)alloc((NT + 1) * 4);
  int*   cnt    = (int*)alloc(NT * 4);
  int*   cursor = (int*)alloc(NT * 4);
  int*   bsum   = (int*)alloc(256 * 4);
  int*   kept0  = (int*)alloc(NT * 4);
  int*   kept1  = (int*)alloc(NT * 4);
  int*   kept2  = (int*)alloc(NT * 4);
  float* gout0  = (float*)alloc(B_ * 256 * 4);
  float* gout1  = (float*)alloc(B_ * 256 * 4);
  float* gout2  = (float*)alloc(B_ * 256 * 4);

  int* keptL[3] = {kept0, kept1, kept2};
  float* goutL[3] = {gout0, gout1, gout2};
  const int K[3] = {1024, 512, 256};
  const int KSH[3] = {10, 9, 8};

  hipMemsetAsync(cnt, 0, NT * 4, stream);

  k_count<<<E_ / 256, 256, 0, stream>>>(dst, cnt);
  k_scan1<<<256, 256, 0, stream>>>(cnt, off, bsum);
  k_scan3<<<256, 256, 0, stream>>>(off, bsum, cnt, cursor, dinv, ds, sws);
  k_fill_srcp<<<E_ / 256, 256, 0, stream>>>(src, dst, cursor, srcp);

  const float* inF = x;
  for (int l = 0; l < 3; ++l) {
    const int* inKept = (l == 0) ? nullptr : keptL[l - 1];
    int inKsh = (l == 0) ? 11 : KSH[l - 1];
    int nrows = (l == 0) ? NT : B_ * K[l - 1];
    int mm_bpgsh = (l == 0) ? 4 : (l == 1 ? 3 : 2);   // (nrows/128)/32 = 16/8/4
    int ag_bpgsh = (l == 0) ? 8 : (l == 1 ? 7 : 6);   // (nrows/8)/32 = 256/128/64
    k_matmul<<<nrows / 128, 256, 0, stream>>>(inF, Wl[l], t, inKept, inKsh, mm_bpgsh);
    k_agg<<<nrows / 8, 256, 0, stream>>>((const float4*)t, off, srcp, dinv, ds, sws,
                                         bl[l], Wpl[l], (float4*)h, t1, inKept, inKsh,
                                         ag_bpgsh);
    k_pool<<<B_, 1024, 0, stream>>>(t1, off, srcp, dinv, ds, sws, bpl[l],
                                    keptL[l], (const float4*)h, goutL[l],
                                    1.f / (float)K[l], K[l]);
    inF = h;
  }
  k_mlp<<<B_, 128, 0, stream>>>(gout0, gout1, gout2,
                                l1W, l1b, l2W, l2b, l3W, l3b, (float*)d_out);
}

// Round 9
// 345.318 us; speedup vs baseline: 1.1624x; 1.0634x over previous
//
#include <hip/hip_runtime.h>
#include <math.h>

// ---------------------------------------------------------------------------
// SAGPool GNN forward: 3x [GCNConv -> SAGPool(top-k) -> readout] + MLP head.
// B=32 graphs x N=2048 nodes; E=524288; 128 feats; K = 1024/512/256.
// R9 changes vs R8 (367us; all kernels <41us; pool readout = 32-block L2 re-read):
//   - readout of layer-l h folded into layer-(l+1) matmul: scanned from the
//     already-staged transposed A-tile (A rows == kept rows), per-tile
//     partials combined in k_mlp. Layer-2 readout stays in pool2.
//   - agg/pool gather loops batched 8-wide: 8 srcp loads -> 8 coefs -> 8 row
//     gathers all in flight (depth-8 MLP of the R2 latency lesson).
//   - XCD relabel extended to CSR build (64 blocks/graph on one XCD).
// ---------------------------------------------------------------------------

namespace {

constexpr int B_  = 32;
constexpr int N_  = 2048;
constexpr int NT  = B_ * N_;        // 65536
constexpr int E_  = B_ * 16384;     // 524288
constexpr int NCLS = 10;
constexpr int AST = 132;            // A-tile LDS row stride (128 + 4 pad)

// blockIdx -> logical block, grouping graphs g%8 per XCD (blockIdx%8=XCD).
// grid = 32*(1<<bpgsh) blocks.
__device__ __forceinline__ int relabel(int bpgsh) {
  int x = blockIdx.x & 7, slot = blockIdx.x >> 3;
  int g = x + 8 * (slot >> bpgsh);
  return (g << bpgsh) + (slot & ((1 << bpgsh) - 1));
}

// ---- CSR build -------------------------------------------------------------
__global__ void k_count(const int* __restrict__ dst, int* __restrict__ cnt) {
  int e = relabel(6) * 256 + threadIdx.x;
  atomicAdd(&cnt[dst[e]], 1);
}

__global__ void k_scan1(const int* __restrict__ cnt, int* __restrict__ off,
                        int* __restrict__ bsum) {
  __shared__ int s[256];
  int t = threadIdx.x;
  int i = blockIdx.x * 256 + t;
  int v = cnt[i];
  s[t] = v;
  __syncthreads();
  for (int d = 1; d < 256; d <<= 1) {
    int add = (t >= d) ? s[t - d] : 0;
    __syncthreads();
    s[t] += add;
    __syncthreads();
  }
  off[i] = s[t] - v;  // exclusive within block
  if (t == 255) bsum[blockIdx.x] = s[255];
}

// adds bsum prefix, writes cursor; layer-0 dinv/ds/sws.
__global__ void k_scan3(int* __restrict__ off, const int* __restrict__ bsum,
                        const int* __restrict__ cnt, int* __restrict__ cursor,
                        float* __restrict__ dinv, float* __restrict__ ds,
                        float* __restrict__ sws) {
  __shared__ int sb[256];
  int t = threadIdx.x;
  sb[t] = bsum[t];
  __syncthreads();
  for (int d = 1; d < 256; d <<= 1) {
    int add = (t >= d) ? sb[t - d] : 0;
    __syncthreads();
    sb[t] += add;
    __syncthreads();
  }
  int prefix = (blockIdx.x == 0) ? 0 : sb[blockIdx.x - 1];
  int i = blockIdx.x * 256 + t;
  int v = off[i] + prefix;
  off[i] = v;
  cursor[i] = v;
  if (i == NT - 1) off[NT] = E_;
  float d = 1.f + (float)cnt[i];
  float di = 1.f / sqrtf(d);
  dinv[i] = di;
  ds[i] = di;        // dinv * scale(=1)
  sws[i] = di * di;  // dinv^2 * scale(=1)
}

__global__ void k_fill_srcp(const int* __restrict__ src, const int* __restrict__ dst,
                            int* __restrict__ cursor, int* __restrict__ srcp) {
  int e = relabel(6) * 256 + threadIdx.x;
  int p = atomicAdd(&cursor[dst[e]], 1);
  srcp[p] = src[e];
}

// ---- dense matmul + fused readout of its input rows ------------------------
// C[rows x 128] = A[rows x 128] @ W. 128x128 tile / 256 thr; 8x8 per thread;
// LDS dbuf, one barrier per chunk. If kept!=null, also computes per-tile
// [max,sum] of (scale[row] .* A-row) from the staged transposed tile.
__global__ __launch_bounds__(256) void k_matmul(const float* __restrict__ A,
                                                const float* __restrict__ W,
                                                float* __restrict__ C,
                                                const int* __restrict__ kept,
                                                int kshift, int bpgsh,
                                                const float* __restrict__ scaleArr,
                                                float* __restrict__ pmx,
                                                float* __restrict__ psm) {
  __shared__ float Ast[2][32 * AST];
  __shared__ float Ws[2][32 * 128];
  __shared__ int rowid[128];
  __shared__ float rsc[128];
  const int tid = threadIdx.x;
  const int tile = relabel(bpgsh);
  if (kept) {
    if (tid < 128) {
      int q = tile * 128 + tid;
      int g = q >> kshift;
      int row = kept[g * N_ + (q - (g << kshift))];
      rowid[tid] = row;
      rsc[tid] = scaleArr[row];
    }
    __syncthreads();
  }
  const int rowq = tid >> 4;   // rows 8*rowq..+7
  const int colq = tid & 15;   // cols {4c..4c+3, 64+4c..+3}
  float4 va[4], vw[4];
#pragma unroll
  for (int i = 0; i < 4; ++i) {
    int idx = tid + 256 * i;
    int row = idx & 127, fq = idx >> 7;
    int gr = kept ? rowid[row] : tile * 128 + row;
    va[i] = *(const float4*)&A[(size_t)gr * 128 + 4 * fq];
  }
#pragma unroll
  for (int i = 0; i < 4; ++i) {
    int idx = tid + 256 * i;
    int kk = idx >> 5, cf = idx & 31;
    vw[i] = *(const float4*)&W[(size_t)kk * 128 + 4 * cf];
  }
#pragma unroll
  for (int i = 0; i < 4; ++i) {
    int idx = tid + 256 * i;
    int row = idx & 127, fq = idx >> 7;
    Ast[0][(4 * fq + 0) * AST + row] = va[i].x;
    Ast[0][(4 * fq + 1) * AST + row] = va[i].y;
    Ast[0][(4 * fq + 2) * AST + row] = va[i].z;
    Ast[0][(4 * fq + 3) * AST + row] = va[i].w;
  }
#pragma unroll
  for (int i = 0; i < 4; ++i) {
    int idx = tid + 256 * i;
    int kk = idx >> 5, cf = idx & 31;
    *(float4*)&Ws[0][kk * 128 + 4 * cf] = vw[i];
  }
  __syncthreads();
  float acc[8][8] = {};
  for (int c = 0; c < 4; ++c) {
    int cur = c & 1;
    if (c < 3) {
      int k0n = 32 * (c + 1);
#pragma unroll
      for (int i = 0; i < 4; ++i) {
        int idx = tid + 256 * i;
        int row = idx & 127, fq = idx >> 7;
        int gr = kept ? rowid[row] : tile * 128 + row;
        va[i] = *(const float4*)&A[(size_t)gr * 128 + k0n + 4 * fq];
      }
#pragma unroll
      for (int i = 0; i < 4; ++i) {
        int idx = tid + 256 * i;
        int kk = idx >> 5, cf = idx & 31;
        vw[i] = *(const float4*)&W[(size_t)(k0n + kk) * 128 + 4 * cf];
      }
    }
#pragma unroll 2
    for (int kk = 0; kk < 32; ++kk) {
      float4 a0 = *(const float4*)&Ast[cur][kk * AST + 8 * rowq];
      float4 a1 = *(const float4*)&Ast[cur][kk * AST + 8 * rowq + 4];
      float4 w0 = *(const float4*)&Ws[cur][kk * 128 + 4 * colq];
      float4 w1 = *(const float4*)&Ws[cur][kk * 128 + 64 + 4 * colq];
      float a[8] = {a0.x, a0.y, a0.z, a0.w, a1.x, a1.y, a1.z, a1.w};
      float w[8] = {w0.x, w0.y, w0.z, w0.w, w1.x, w1.y, w1.z, w1.w};
#pragma unroll
      for (int r = 0; r < 8; ++r)
#pragma unroll
        for (int cc = 0; cc < 8; ++cc) acc[r][cc] += a[r] * w[cc];
    }
    // fused readout of this chunk's 32 feats from the staged tile
    if (kept) {
      int kkf = tid >> 3;            // feat within chunk, 0..31
      int r0 = (tid & 7) * 16;       // 16-row slice per thread
      float mxv = -INFINITY, smv = 0.f;
#pragma unroll
      for (int rr = 0; rr < 16; rr += 4) {
        float4 av = *(const float4*)&Ast[cur][kkf * AST + r0 + rr];
        float4 s4 = *(const float4*)&rsc[r0 + rr];
        float v0 = av.x * s4.x, v1 = av.y * s4.y;
        float v2 = av.z * s4.z, v3 = av.w * s4.w;
        mxv = fmaxf(fmaxf(fmaxf(mxv, v0), fmaxf(v1, v2)), v3);
        smv += v0 + v1 + v2 + v3;
      }
#pragma unroll
      for (int o = 4; o >= 1; o >>= 1) {
        mxv = fmaxf(mxv, __shfl_down(mxv, o));
        smv += __shfl_down(smv, o);
      }
      if ((tid & 7) == 0) {
        pmx[(size_t)tile * 128 + 32 * c + kkf] = mxv;
        psm[(size_t)tile * 128 + 32 * c + kkf] = smv;
      }
    }
    if (c < 3) {
      int nxt = cur ^ 1;
#pragma unroll
      for (int i = 0; i < 4; ++i) {
        int idx = tid + 256 * i;
        int row = idx & 127, fq = idx >> 7;
        Ast[nxt][(4 * fq + 0) * AST + row] = va[i].x;
        Ast[nxt][(4 * fq + 1) * AST + row] = va[i].y;
        Ast[nxt][(4 * fq + 2) * AST + row] = va[i].z;
        Ast[nxt][(4 * fq + 3) * AST + row] = va[i].w;
      }
#pragma unroll
      for (int i = 0; i < 4; ++i) {
        int idx = tid + 256 * i;
        int kk = idx >> 5, cf = idx & 31;
        *(float4*)&Ws[nxt][kk * 128 + 4 * cf] = vw[i];
      }
      __syncthreads();
    }
  }
#pragma unroll
  for (int r = 0; r < 8; ++r) {
    int gr = kept ? rowid[8 * rowq + r] : tile * 128 + 8 * rowq + r;
    float* Crow = &C[(size_t)gr * 128];
    *(float4*)&Crow[4 * colq] = make_float4(acc[r][0], acc[r][1], acc[r][2], acc[r][3]);
    *(float4*)&Crow[64 + 4 * colq] = make_float4(acc[r][4], acc[r][5], acc[r][6], acc[r][7]);
  }
}

// ---- feature aggregation + bias + relu + fused score matvec ---------------
// coef = ds[src]*dinv[node]; self = sws[node]. 8-deep load batching.
__global__ __launch_bounds__(256) void k_agg(const float4* __restrict__ t4,
                                             const int* __restrict__ off,
                                             const int* __restrict__ srcp,
                                             const float* __restrict__ dinv,
                                             const float* __restrict__ ds,
                                             const float* __restrict__ sws,
                                             const float* __restrict__ bias,
                                             const float* __restrict__ Wp,
                                             float4* __restrict__ h4,
                                             float* __restrict__ t1,
                                             const int* __restrict__ kept,
                                             int kshift, int bpgsh) {
  int q = relabel(bpgsh) * 8 + (threadIdx.x >> 5);
  int node;
  if (kept) {
    int g = q >> kshift;
    node = kept[g * N_ + (q - (g << kshift))];
  } else {
    node = q;
  }
  const int lane = threadIdx.x & 31;
  const float dvi = dinv[node];
  float sw = sws[node];
  float4 self = t4[(size_t)node * 32 + lane];
  float4 acc = make_float4(sw * self.x, sw * self.y, sw * self.z, sw * self.w);
  int s = off[node], en = off[node + 1];
  int j = s;
  for (; j + 8 <= en; j += 8) {
    int sv[8];
    float cv[8];
#pragma unroll
    for (int i = 0; i < 8; ++i) sv[i] = srcp[j + i];
#pragma unroll
    for (int i = 0; i < 8; ++i) cv[i] = ds[sv[i]] * dvi;
#pragma unroll
    for (int i = 0; i < 8; ++i) {
      if (cv[i] != 0.f) {
        float4 r = t4[(size_t)sv[i] * 32 + lane];
        acc.x += cv[i] * r.x; acc.y += cv[i] * r.y;
        acc.z += cv[i] * r.z; acc.w += cv[i] * r.w;
      }
    }
  }
  for (; j < en; ++j) {
    int s0 = srcp[j];
    float c0 = ds[s0] * dvi;
    if (c0 != 0.f) {
      float4 r0 = t4[(size_t)s0 * 32 + lane];
      acc.x += c0 * r0.x; acc.y += c0 * r0.y; acc.z += c0 * r0.z; acc.w += c0 * r0.w;
    }
  }
  float4 b4 = ((const float4*)bias)[lane];
  acc.x = fmaxf(acc.x + b4.x, 0.f);
  acc.y = fmaxf(acc.y + b4.y, 0.f);
  acc.z = fmaxf(acc.z + b4.z, 0.f);
  acc.w = fmaxf(acc.w + b4.w, 0.f);
  h4[(size_t)node * 32 + lane] = acc;
  float4 wp = ((const float4*)Wp)[lane];
  float part = acc.x * wp.x + acc.y * wp.y + acc.z * wp.z + acc.w * wp.w;
#pragma unroll
  for (int o = 16; o > 0; o >>= 1) part += __shfl_down(part, o, 32);
  if (lane == 0) t1[node] = part;
}

// ---- fused pool (+ layer-2 readout): score agg, radix top-k, scale, kept,
// next-layer dinv/ds/sws. One block per graph (relabeled g%8 per XCD).
__global__ __launch_bounds__(1024) void k_pool(const float* __restrict__ t1,
                                               const int* __restrict__ off,
                                               const int* __restrict__ srcp,
                                               float* __restrict__ dinv,
                                               float* __restrict__ ds,
                                               float* __restrict__ sws,
                                               float* __restrict__ scale,
                                               const float* __restrict__ bp,
                                               int* __restrict__ kept,
                                               const float4* __restrict__ h4,
                                               float* __restrict__ gout,
                                               float invk, int k) {
  __shared__ float st1[2048];       // t1 in; scale after selection
  __shared__ float sdv[2048];
  __shared__ float skp[2048];
  __shared__ int skept[1024];
  __shared__ unsigned rephist[4096];  // 16 waves x 256 bins; reused as red[]
  __shared__ unsigned ebits[64];
  __shared__ int wsum[16];
  __shared__ unsigned bc_digit, bc_prev;
  const int g = (blockIdx.x & 7) + 8 * (blockIdx.x >> 3);
  const int t = threadIdx.x;
  const int base = g * N_;
  st1[t] = t1[base + t];
  st1[t + 1024] = t1[base + t + 1024];
  sdv[t] = dinv[base + t];
  sdv[t + 1024] = dinv[base + t + 1024];
  if (t < 64) ebits[t] = 0u;
#pragma unroll
  for (int i = 0; i < 4; ++i) rephist[t + 1024 * i] = 0u;
  __syncthreads();
  float raw[2];
  unsigned key[2];
  float bpv = bp[0];
#pragma unroll
  for (int q = 0; q < 2; ++q) {
    int n = t + q * 1024;
    float di = sdv[n];
    float a = 0.f;
    int s = off[base + n], en = off[base + n + 1];
    int j = s;
    for (; j + 8 <= en; j += 8) {
      int sv[8];
#pragma unroll
      for (int i = 0; i < 8; ++i) sv[i] = srcp[j + i] - base;
#pragma unroll
      for (int i = 0; i < 8; ++i) a += sdv[sv[i]] * st1[sv[i]];
    }
    for (; j < en; ++j) {
      int sl = srcp[j] - base;
      a += sdv[sl] * st1[sl];
    }
    raw[q] = di * di * st1[n] + di * a + bpv;  // selfw == dinv^2
    unsigned u = __float_as_uint(raw[q]);
    u = (u & 0x80000000u) ? ~u : (u | 0x80000000u);
    u = ~u;  // descending
    if (di <= 0.f) u = 0xFFFFFFFFu;
    key[q] = u;
  }
  // radix-select k-th largest score
  unsigned prefix = 0u, rem = (unsigned)k;
  const int wv = t >> 6;
  for (int shift = 24; shift >= 0; shift -= 8) {
    unsigned mask = (shift == 24) ? 0u : (0xFFFFFFFFu << (shift + 8));
#pragma unroll
    for (int q = 0; q < 2; ++q)
      if ((key[q] & mask) == prefix)
        atomicAdd(&rephist[(wv << 8) + ((key[q] >> shift) & 255u)], 1u);
    __syncthreads();
    unsigned binv = 0u, v = 0u;
    if (t < 256) {
#pragma unroll
      for (int w = 0; w < 16; ++w) binv += rephist[(w << 8) + t];
      v = binv;
#pragma unroll
      for (int o = 1; o < 64; o <<= 1) {
        unsigned nv = __shfl_up(v, o);
        if ((t & 63) >= o) v += nv;
      }
      if ((t & 63) == 63) wsum[t >> 6] = (int)v;
    }
    __syncthreads();
    if (t < 256) {
      unsigned pre = 0u;
      int w4 = t >> 6;
      for (int u = 0; u < w4; ++u) pre += (unsigned)wsum[u];
      unsigned inc = v + pre, exc = inc - binv;
      if (inc >= rem && exc < rem) { bc_digit = (unsigned)t; bc_prev = exc; }
    }
    __syncthreads();
    if (shift > 0) {
#pragma unroll
      for (int i = 0; i < 4; ++i) rephist[t + 1024 * i] = 0u;
    }
    __syncthreads();
    prefix |= bc_digit << shift;
    rem -= bc_prev;
  }
  const unsigned Tkey = prefix;
  const int need = (int)rem;  // ties, lowest index first
#pragma unroll
  for (int q = 0; q < 2; ++q) {
    int n = t + q * 1024;
    if (key[q] == Tkey) atomicOr(&ebits[n >> 5], 1u << (n & 31));
  }
  __syncthreads();
#pragma unroll
  for (int q = 0; q < 2; ++q) {
    int n = t + q * 1024;
    float kp;
    if (key[q] < Tkey) {
      kp = 1.f;
    } else if (key[q] == Tkey) {
      int w = n >> 5;
      int rank = __popc(ebits[w] & ((1u << (n & 31)) - 1u));
      for (int u = 0; u < w; ++u) rank += __popc(ebits[u]);
      kp = (rank < need) ? 1.f : 0.f;
    } else {
      kp = 0.f;
    }
    skp[n] = kp;
    float sc = kp * tanhf(raw[q]);
    st1[n] = sc;              // scale in LDS
    scale[base + n] = sc;     // scale to global (read by next matmul readout)
  }
  __syncthreads();
  // compacted kept list -> global + LDS
  {
    int lane = t & 63, w = t >> 6;
    int a0 = (int)skp[2 * t], a1 = (int)skp[2 * t + 1];
    int ps = a0 + a1;
    int v = ps;
#pragma unroll
    for (int o = 1; o < 64; o <<= 1) {
      int nv = __shfl_up(v, o);
      if (lane >= o) v += nv;
    }
    if (lane == 63) wsum[w] = v;
    __syncthreads();
    if (t == 0) {
      int accv = 0;
      for (int i = 0; i < 16; ++i) { int tmp = wsum[i]; wsum[i] = accv; accv += tmp; }
    }
    __syncthreads();
    int excl = wsum[w] + v - ps;
    if (a0) { kept[base + excl] = base + 2 * t; skept[excl] = base + 2 * t; }
    if (a1) { kept[base + excl + a0] = base + 2 * t + 1; skept[excl + a0] = base + 2 * t + 1; }
  }
  // next-layer dinv/ds/sws from new nmask (in LDS), 8-deep batched
#pragma unroll
  for (int q = 0; q < 2; ++q) {
    int n = t + q * 1024;
    float nm = skp[n];
    float d = nm;
    int s = off[base + n], en = off[base + n + 1];
    int j = s;
    for (; j + 8 <= en; j += 8) {
      int sv[8];
#pragma unroll
      for (int i = 0; i < 8; ++i) sv[i] = srcp[j + i] - base;
#pragma unroll
      for (int i = 0; i < 8; ++i) d += skp[sv[i]];
    }
    for (; j < en; ++j) d += skp[srcp[j] - base];
    float di = (nm > 0.f) ? (1.f / sqrtf(d)) : 0.f;
    float sc = st1[n];
    dinv[base + n] = di;
    ds[base + n] = di * sc;
    sws[base + n] = di * di * sc;
  }
  if (!gout) return;
  __syncthreads();
  // layer-2 readout over kept list: [max, mean] of scale.*h
  const int lane = t & 31, ng = t >> 5;
  float4 mx = make_float4(-INFINITY, -INFINITY, -INFINITY, -INFINITY);
  float4 sm = make_float4(0.f, 0.f, 0.f, 0.f);
  for (int i = ng; i < k; i += 32) {
    int node = skept[i];
    float sc = st1[node - base];
    float4 v = h4[(size_t)node * 32 + lane];
    v.x *= sc; v.y *= sc; v.z *= sc; v.w *= sc;
    mx.x = fmaxf(mx.x, v.x); mx.y = fmaxf(mx.y, v.y);
    mx.z = fmaxf(mx.z, v.z); mx.w = fmaxf(mx.w, v.w);
    sm.x += v.x; sm.y += v.y; sm.z += v.z; sm.w += v.w;
  }
  float4* red = (float4*)rephist;
  for (int d = 16; d >= 1; d >>= 1) {
    if (ng >= d && ng < 2 * d) {
      red[(ng - d) * 32 + lane] = mx;
      red[512 + (ng - d) * 32 + lane] = sm;
    }
    __syncthreads();
    if (ng < d) {
      float4 omx = red[ng * 32 + lane];
      float4 osm = red[512 + ng * 32 + lane];
      mx.x = fmaxf(mx.x, omx.x); mx.y = fmaxf(mx.y, omx.y);
      mx.z = fmaxf(mx.z, omx.z); mx.w = fmaxf(mx.w, omx.w);
      sm.x += osm.x; sm.y += osm.y; sm.z += osm.z; sm.w += osm.w;
    }
    __syncthreads();
  }
  if (ng == 0) {
    gout[g * 256 + 4 * lane + 0] = mx.x;
    gout[g * 256 + 4 * lane + 1] = mx.y;
    gout[g * 256 + 4 * lane + 2] = mx.z;
    gout[g * 256 + 4 * lane + 3] = mx.w;
    gout[g * 256 + 128 + 4 * lane + 0] = sm.x * invk;
    gout[g * 256 + 128 + 4 * lane + 1] = sm.y * invk;
    gout[g * 256 + 128 + 4 * lane + 2] = sm.z * invk;
    gout[g * 256 + 128 + 4 * lane + 3] = sm.w * invk;
  }
}

// ---- MLP head + log_softmax (combines matmul-readout partials) -------------
__global__ __launch_bounds__(128) void k_mlp(const float* __restrict__ pmxA,
                                             const float* __restrict__ psmA,
                                             const float* __restrict__ pmxB,
                                             const float* __restrict__ psmB,
                                             const float* __restrict__ goutC,
                                             const float* __restrict__ W1,
                                             const float* __restrict__ b1,
                                             const float* __restrict__ W2,
                                             const float* __restrict__ b2,
                                             const float* __restrict__ W3,
                                             const float* __restrict__ b3,
                                             float* __restrict__ out) {
  __shared__ float gr[256], o1[128], o2[64], o3[NCLS];
  int g = blockIdx.x, t = threadIdx.x;
  float mxA = -INFINITY, smA = 0.f;
#pragma unroll
  for (int p = 0; p < 8; ++p) {
    mxA = fmaxf(mxA, pmxA[(size_t)(g * 8 + p) * 128 + t]);
    smA += psmA[(size_t)(g * 8 + p) * 128 + t];
  }
  float mxB = -INFINITY, smB = 0.f;
#pragma unroll
  for (int p = 0; p < 4; ++p) {
    mxB = fmaxf(mxB, pmxB[(size_t)(g * 4 + p) * 128 + t]);
    smB += psmB[(size_t)(g * 4 + p) * 128 + t];
  }
  gr[t] = mxA + mxB + goutC[g * 256 + t];
  gr[t + 128] = smA * (1.f / 1024.f) + smB * (1.f / 512.f) + goutC[g * 256 + 128 + t];
  __syncthreads();
  float a = b1[t];
  for (int kk = 0; kk < 256; ++kk) a += gr[kk] * W1[kk * 128 + t];
  o1[t] = fmaxf(a, 0.f);
  __syncthreads();
  if (t < 64) {
    float a2 = b2[t];
    for (int kk = 0; kk < 128; ++kk) a2 += o1[kk] * W2[kk * 64 + t];
    o2[t] = fmaxf(a2, 0.f);
  }
  __syncthreads();
  if (t < NCLS) {
    float a3 = b3[t];
    for (int kk = 0; kk < 64; ++kk) a3 += o2[kk] * W3[kk * NCLS + t];
    o3[t] = a3;
  }
  __syncthreads();
  if (t == 0) {
    float m = -INFINITY;
    for (int c = 0; c < NCLS; ++c) m = fmaxf(m, o3[c]);
    float sum = 0.f;
    for (int c = 0; c < NCLS; ++c) sum += expf(o3[c] - m);
    float lse = logf(sum);
    for (int c = 0; c < NCLS; ++c) out[g * NCLS + c] = o3[c] - m - lse;
  }
}

}  // namespace

extern "C" void kernel_launch(void* const* d_in, const int* in_sizes, int n_in,
                              void* d_out, int out_size, void* d_ws, size_t ws_size,
                              hipStream_t stream) {
  const float* x = (const float*)d_in[0];
  const int* ei = (const int*)d_in[1];
  const int* src = ei;
  const int* dst = ei + E_;
  const float* Wl[3]  = {(const float*)d_in[3], (const float*)d_in[7], (const float*)d_in[11]};
  const float* bl[3]  = {(const float*)d_in[4], (const float*)d_in[8], (const float*)d_in[12]};
  const float* Wpl[3] = {(const float*)d_in[5], (const float*)d_in[9], (const float*)d_in[13]};
  const float* bpl[3] = {(const float*)d_in[6], (const float*)d_in[10], (const float*)d_in[14]};
  const float* l1W = (const float*)d_in[15];
  const float* l1b = (const float*)d_in[16];
  const float* l2W = (const float*)d_in[17];
  const float* l2b = (const float*)d_in[18];
  const float* l3W = (const float*)d_in[19];
  const float* l3b = (const float*)d_in[20];

  char* p = (char*)d_ws;
  auto alloc = [&](size_t bytes) -> void* {
    void* r = (void*)p;
    p += (bytes + 255) & ~size_t(255);
    return r;
  };
  float* h      = (float*)alloc((size_t)NT * 128 * 4);
  float* t      = (float*)alloc((size_t)NT * 128 * 4);
  float* dinv   = (float*)alloc(NT * 4);
  float* ds     = (float*)alloc(NT * 4);
  float* sws    = (float*)alloc(NT * 4);
  float* scale  = (float*)alloc(NT * 4);
  float* t1     = (float*)alloc(NT * 4);
  int*   srcp   = (int*)alloc(E_ * 4);
  int*   off    = (int*)alloc((NT + 1) * 4);
  int*   cnt    = (int*)alloc(NT * 4);
  int*   cursor = (int*)alloc(NT * 4);
  int*   bsum   = (int*)alloc(256 * 4);
  int*   kept0  = (int*)alloc(NT * 4);
  int*   kept1  = (int*)alloc(NT * 4);
  int*   kept2  = (int*)alloc(NT * 4);
  float* pmxA   = (float*)alloc(256 * 128 * 4);
  float* psmA   = (float*)alloc(256 * 128 * 4);
  float* pmxB   = (float*)alloc(128 * 128 * 4);
  float* psmB   = (float*)alloc(128 * 128 * 4);
  float* goutC  = (float*)alloc(B_ * 256 * 4);

  int* keptL[3] = {kept0, kept1, kept2};
  const int K[3] = {1024, 512, 256};
  const int KSH[3] = {10, 9, 8};
  float* pmxL[3] = {nullptr, pmxA, pmxB};
  float* psmL[3] = {nullptr, psmA, psmB};

  hipMemsetAsync(cnt, 0, NT * 4, stream);

  k_count<<<E_ / 256, 256, 0, stream>>>(dst, cnt);
  k_scan1<<<256, 256, 0, stream>>>(cnt, off, bsum);
  k_scan3<<<256, 256, 0, stream>>>(off, bsum, cnt, cursor, dinv, ds, sws);
  k_fill_srcp<<<E_ / 256, 256, 0, stream>>>(src, dst, cursor, srcp);

  const float* inF = x;
  for (int l = 0; l < 3; ++l) {
    const int* inKept = (l == 0) ? nullptr : keptL[l - 1];
    int inKsh = (l == 0) ? 11 : KSH[l - 1];
    int nrows = (l == 0) ? NT : B_ * K[l - 1];
    int mm_bpgsh = (l == 0) ? 4 : (l == 1 ? 3 : 2);   // 512/256/128 blocks
    int ag_bpgsh = (l == 0) ? 8 : (l == 1 ? 7 : 6);   // 8192/4096/2048 blocks
    k_matmul<<<nrows / 128, 256, 0, stream>>>(inF, Wl[l], t, inKept, inKsh, mm_bpgsh,
                                              scale, pmxL[l], psmL[l]);
    k_agg<<<nrows / 8, 256, 0, stream>>>((const float4*)t, off, srcp, dinv, ds, sws,
                                         bl[l], Wpl[l], (float4*)h, t1, inKept, inKsh,
                                         ag_bpgsh);
    k_pool<<<B_, 1024, 0, stream>>>(t1, off, srcp, dinv, ds, sws, scale, bpl[l],
                                    keptL[l], (const float4*)h,
                                    (l == 2) ? goutC : nullptr,
                                    1.f / (float)K[l], K[l]);
    inF = h;
  }
  k_mlp<<<B_, 128, 0, stream>>>(pmxA, psmA, pmxB, psmB, goutC,
                                l1W, l1b, l2W, l2b, l3W, l3b, (float*)d_out);
}